// Round 2
// baseline (906.668 us; speedup 1.0000x reference)
//
#include <hip/hip_runtime.h>

typedef unsigned short u16;
typedef unsigned int u32;
typedef __attribute__((ext_vector_type(8))) short bf16x8;
typedef __attribute__((ext_vector_type(4))) float f32x4;

#define BB 4096
#define NS 26
#define DNS 13
#define DD 16
#define VV 100000
#define FF 128
#define NF 39
#define BD 65536
#define DIN_PAD 448

__device__ __forceinline__ float bf2f(u16 x) {
    union { u32 u; float f; } v; v.u = ((u32)x) << 16; return v.f;
}
__device__ __forceinline__ u16 f2bf(float f) {
    union { float f; u32 u; } v; v.f = f;
    u32 u = v.u;
    u32 r = (u + 0x7fffu + ((u >> 16) & 1u)) >> 16;
    return (u16)r;
}

// ---------------- prep kernels (f32 in -> bf16 workspace) ----------------

__global__ void prep_x0_k(const float* __restrict__ emb_W, const int* __restrict__ disc,
                          const float* __restrict__ dense_x, const float* __restrict__ dense_proj,
                          u16* __restrict__ x0) {
    int e = blockIdx.x * 256 + threadIdx.x;   // BD*64
    int c = e & 63;
    int j = e >> 6;
    int b = j >> 4, d = j & 15;
    float v = 0.f;
    if (c < NS) {
        int ix = disc[b * NS + c];
        v = emb_W[((size_t)c * VV + ix) * DD + d];
    } else if (c < NF) {
        int q = c - NS;
        v = dense_x[b * DNS + q] * dense_proj[q * DD + d];
    }
    x0[e] = f2bf(v);
}

__global__ void prep_h0_k(const float* __restrict__ emb_W, const int* __restrict__ disc,
                          const float* __restrict__ dense_x, u16* __restrict__ h0) {
    int e = blockIdx.x * 256 + threadIdx.x;   // B*448
    int col = e % DIN_PAD;
    int b = e / DIN_PAD;
    float v = 0.f;
    if (col < NS * DD) {
        int n = col >> 4, d = col & 15;
        int ix = disc[b * NS + n];
        v = emb_W[((size_t)n * VV + ix) * DD + d];
    } else if (col < NS * DD + DNS) {
        v = dense_x[b * DNS + col - NS * DD];
    }
    h0[e] = f2bf(v);
}

__global__ void transpose_pad_k(const float* __restrict__ src, u16* __restrict__ dst,
                                int K, int Nn, int Kpad) {
    int e = blockIdx.x * 256 + threadIdx.x;   // Nn*Kpad
    int n = e / Kpad, k = e % Kpad;
    dst[e] = (k < K) ? f2bf(src[(size_t)k * Nn + n]) : (u16)0;
}

// cin weight rearrange: dst[n][f][c(pad)] = W[f,c,n]
__global__ void cinw_k(const float* __restrict__ src, u16* __restrict__ dst, int C, int Cpad) {
    int e = blockIdx.x * 256 + threadIdx.x;   // 39*128*Cpad
    int n = e / (128 * Cpad);
    int rem = e % (128 * Cpad);
    int f = rem / Cpad, c = rem % Cpad;
    dst[e] = (c < C) ? f2bf(src[((size_t)f * C + c) * NF + n]) : (u16)0;
}

// ---------------- DNN GEMM: C = relu(bn(A@W + bias)) ----------------
// A [M,K] bf16 (K mult of 32), Bt [N,K] bf16 (pre-transposed W), C [M,N] bf16
__global__ __launch_bounds__(256) void gemm_bn_relu_k(
    const u16* __restrict__ A, const u16* __restrict__ Bt, u16* __restrict__ C,
    int M, int N, int K,
    const float* __restrict__ bias, const float* __restrict__ g, const float* __restrict__ bb)
{
    __shared__ u16 la[64 * 40];
    __shared__ u16 lb[64 * 40];
    const int tid = threadIdx.x;
    const int lane = tid & 63, wave = tid >> 6;
    const int quad = lane >> 4, l16 = lane & 15;
    const int m0 = blockIdx.y * 64, n0 = blockIdx.x * 64;
    const f32x4 fzero = {0.f, 0.f, 0.f, 0.f};
    f32x4 acc[4];
    #pragma unroll
    for (int t = 0; t < 4; ++t) acc[t] = fzero;
    const int r = tid >> 2, cc = (tid & 3) * 8;
    for (int k0 = 0; k0 < K; k0 += 32) {
        __syncthreads();
        *(int4*)&la[r * 40 + cc] = *(const int4*)&A[(size_t)(m0 + r) * K + k0 + cc];
        *(int4*)&lb[r * 40 + cc] = *(const int4*)&Bt[(size_t)(n0 + r) * K + k0 + cc];
        __syncthreads();
        bf16x8 af = *(const bf16x8*)&la[(wave * 16 + l16) * 40 + quad * 8];
        #pragma unroll
        for (int t = 0; t < 4; ++t) {
            bf16x8 bfm = *(const bf16x8*)&lb[(t * 16 + l16) * 40 + quad * 8];
            acc[t] = __builtin_amdgcn_mfma_f32_16x16x32_bf16(af, bfm, acc[t], 0, 0, 0);
        }
    }
    const float rs = rsqrtf(1.f + 1e-5f);
    #pragma unroll
    for (int t = 0; t < 4; ++t) {
        int n = n0 + t * 16 + l16;
        float bi = bias[n];
        float sc = g[n] * rs;
        float b2 = bb[n];
        #pragma unroll
        for (int rr = 0; rr < 4; ++rr) {
            int m = m0 + wave * 16 + quad * 4 + rr;
            float v = (acc[t][rr] + bi) * sc + b2;
            v = fmaxf(v, 0.f);
            C[(size_t)m * N + n] = f2bf(v);
        }
    }
}

// ---------------- CIN layer ----------------
// Out[j,f] = sum_n x0[j,n] * sum_c W[f,c,n]*Xj[j,c],  j = b*16+d
// Xj [BD][CPAD] bf16, X0w [BD][64] bf16, Wr [39][128][CPAD] bf16, Out [BD][128] bf16
template <int CPAD>
__global__ __launch_bounds__(256, 1) void cin_layer_k(
    const u16* __restrict__ Xj, const u16* __restrict__ X0w,
    const u16* __restrict__ Wr, u16* __restrict__ Out)
{
    constexpr int J = 128;
    constexpr int LDW = CPAD + 8;            // LDS stride (16B aligned rows, bank-spread)
    constexpr int NCH = CPAD / 32;           // K-chunks of 32 per MFMA group
    constexpr int CH_ROW = CPAD / 8;         // 16B chunks per row
    constexpr int WCH = 128 * CH_ROW / 256;  // W_n chunks per thread
    __shared__ u16 smem[128 * LDW * 2 + 128 * 72];
    u16* lds_w  = smem;
    u16* lds_xj = smem + 128 * LDW;
    u16* lds_x0 = smem + 2 * 128 * LDW;
    const int tid = threadIdx.x;
    const int lane = tid & 63, wave = tid >> 6;
    const int quad = lane >> 4, l16 = lane & 15;
    const size_t j0 = (size_t)blockIdx.x * J;
    const f32x4 fzero = {0.f, 0.f, 0.f, 0.f};

    // stage Xj tile [J][CPAD]
    for (int ch = tid; ch < J * CH_ROW; ch += 256) {
        int rr = ch / CH_ROW, c = (ch % CH_ROW) * 8;
        *(int4*)&lds_xj[rr * LDW + c] = *(const int4*)&Xj[(j0 + rr) * CPAD + c];
    }
    // stage x0 tile [J][64] at stride 72
    for (int ch = tid; ch < J * 8; ch += 256) {
        int rr = ch >> 3, c = (ch & 7) * 8;
        *(int4*)&lds_x0[rr * 72 + c] = *(const int4*)&X0w[(j0 + rr) * 64 + c];
    }
    // prefetch W_0 into registers
    int4 wreg[WCH];
    #pragma unroll
    for (int i = 0; i < WCH; ++i) {
        int ch = tid + i * 256;
        int f = ch / CH_ROW, c = (ch % CH_ROW) * 8;
        wreg[i] = *(const int4*)&Wr[(size_t)f * CPAD + c];
    }
    f32x4 acc[8][2];
    #pragma unroll
    for (int js = 0; js < 8; ++js) { acc[js][0] = fzero; acc[js][1] = fzero; }

    for (int n = 0; n < NF; ++n) {
        __syncthreads();                 // prior readers of lds_w done (covers xj/x0 staging at n=0)
        #pragma unroll
        for (int i = 0; i < WCH; ++i) {
            int ch = tid + i * 256;
            int f = ch / CH_ROW, c = (ch % CH_ROW) * 8;
            *(int4*)&lds_w[f * LDW + c] = wreg[i];
        }
        __syncthreads();                 // lds_w ready
        if (n + 1 < NF) {                // prefetch next W_n (in flight during compute)
            const u16* wn = Wr + (size_t)(n + 1) * 128 * CPAD;
            #pragma unroll
            for (int i = 0; i < WCH; ++i) {
                int ch = tid + i * 256;
                int f = ch / CH_ROW, c = (ch % CH_ROW) * 8;
                wreg[i] = *(const int4*)&wn[(size_t)f * CPAD + c];
            }
        }
        // A-frags (W_n rows for this wave's 32 f), held across j-subtiles
        bf16x8 afr[2][NCH];
        #pragma unroll
        for (int ms = 0; ms < 2; ++ms) {
            #pragma unroll
            for (int kc = 0; kc < NCH; ++kc)
                afr[ms][kc] = *(const bf16x8*)&lds_w[(wave * 32 + ms * 16 + l16) * LDW + kc * 32 + quad * 8];
        }
        #pragma unroll
        for (int js = 0; js < 8; ++js) {
            int jr = js * 16 + l16;
            f32x4 s0 = fzero;
            f32x4 s1 = fzero;
            #pragma unroll
            for (int kc = 0; kc < NCH; ++kc) {
                bf16x8 bfr = *(const bf16x8*)&lds_xj[jr * LDW + kc * 32 + quad * 8];
                s0 = __builtin_amdgcn_mfma_f32_16x16x32_bf16(afr[0][kc], bfr, s0, 0, 0, 0);
                s1 = __builtin_amdgcn_mfma_f32_16x16x32_bf16(afr[1][kc], bfr, s1, 0, 0, 0);
            }
            float xv = bf2f(lds_x0[jr * 72 + n]);
            acc[js][0] += xv * s0;
            acc[js][1] += xv * s1;
        }
    }
    // epilogue: transpose through LDS ([j][f], stride 136) for coalesced stores
    __syncthreads();
    #pragma unroll
    for (int js = 0; js < 8; ++js) {
        int jr = js * 16 + l16;
        #pragma unroll
        for (int ms = 0; ms < 2; ++ms) {
            int m = wave * 32 + ms * 16 + quad * 4;
            f32x4 v = acc[js][ms];
            u32 p0 = (u32)f2bf(v[0]) | ((u32)f2bf(v[1]) << 16);
            u32 p1 = (u32)f2bf(v[2]) | ((u32)f2bf(v[3]) << 16);
            *(u32*)&smem[jr * 136 + m] = p0;
            *(u32*)&smem[jr * 136 + m + 2] = p1;
        }
    }
    __syncthreads();
    for (int ch = tid; ch < J * 16; ch += 256) {
        int rr = ch >> 4, c = (ch & 15) * 8;
        *(int4*)&Out[(j0 + rr) * 128 + c] = *(const int4*)&smem[rr * 136 + c];
    }
}

// ---------------- final combine ----------------
__global__ __launch_bounds__(64) void final_k(
    const float* __restrict__ dense_x, const int* __restrict__ disc,
    const float* __restrict__ lin_emb, const float* __restrict__ dense_W,
    const float* __restrict__ dense_b, const u16* __restrict__ h3,
    const float* __restrict__ Wout, const float* __restrict__ bout,
    const u16* __restrict__ out0, const u16* __restrict__ out1, const u16* __restrict__ out2,
    const float* __restrict__ cw, const float* __restrict__ cb, float* __restrict__ out)
{
    const int b = blockIdx.x;
    const int lane = threadIdx.x;
    float t = 0.f;
    if (lane < DNS) {
        t += dense_x[b * DNS + lane] * dense_W[lane];
    } else if (lane < DNS + NS) {
        int i = lane - DNS;
        t += lin_emb[(size_t)i * VV + disc[b * NS + i]];
    }
    const u16* hr = h3 + (size_t)b * 256;
    #pragma unroll
    for (int rr = 0; rr < 4; ++rr) {
        int c = lane * 4 + rr;
        t += bf2f(hr[c]) * Wout[c];
    }
    const u16* obs[3] = {out0, out1, out2};
    #pragma unroll
    for (int L = 0; L < 3; ++L) {
        const u16* ob = obs[L] + (size_t)b * 16 * 128;
        #pragma unroll
        for (int h = 0; h < 2; ++h) {
            int f = lane + h * 64;
            float p = 0.f;
            #pragma unroll
            for (int d = 0; d < 16; ++d) p += bf2f(ob[d * 128 + f]);
            t += p * cw[L * 128 + f];
        }
    }
    #pragma unroll
    for (int off = 32; off > 0; off >>= 1) t += __shfl_down(t, off, 64);
    if (lane == 0) out[b] = t + dense_b[0] + bout[0] + cb[0];
}

// ---------------- launch ----------------
extern "C" void kernel_launch(void* const* d_in, const int* in_sizes, int n_in,
                              void* d_out, int out_size, void* d_ws, size_t ws_size,
                              hipStream_t stream) {
    const float* dense_x = (const float*)d_in[0];
    const int* disc      = (const int*)d_in[1];
    const float* lin_emb = (const float*)d_in[2];
    const float* emb_W   = (const float*)d_in[3];
    const float* dense_W = (const float*)d_in[4];
    const float* dense_b = (const float*)d_in[5];
    const float* W1  = (const float*)d_in[6];
    const float* b1  = (const float*)d_in[7];
    const float* g1  = (const float*)d_in[8];
    const float* bb1 = (const float*)d_in[9];
    const float* W2  = (const float*)d_in[10];
    const float* b2  = (const float*)d_in[11];
    const float* g2  = (const float*)d_in[12];
    const float* bb2 = (const float*)d_in[13];
    const float* W3  = (const float*)d_in[14];
    const float* b3  = (const float*)d_in[15];
    const float* g3  = (const float*)d_in[16];
    const float* bb3 = (const float*)d_in[17];
    const float* Wout = (const float*)d_in[18];
    const float* bout = (const float*)d_in[19];
    const float* dense_proj = (const float*)d_in[20];
    const float* cin_W0 = (const float*)d_in[21];
    const float* cin_W1 = (const float*)d_in[22];
    const float* cin_W2 = (const float*)d_in[23];
    const float* cin_ow = (const float*)d_in[24];
    const float* cin_ob = (const float*)d_in[25];

    u16* p = (u16*)d_ws;
    u16* x0  = p; p += (size_t)BD * 64;
    u16* h0  = p; p += (size_t)BB * DIN_PAD;
    u16* h1  = p; p += (size_t)BB * 1024;
    u16* h2  = p; p += (size_t)BB * 512;
    u16* h3  = p; p += (size_t)BB * 256;
    u16* W1t = p; p += (size_t)1024 * DIN_PAD;
    u16* W2t = p; p += (size_t)512 * 1024;
    u16* W3t = p; p += (size_t)256 * 512;
    u16* W0r = p; p += (size_t)NF * 128 * 64;
    u16* W1r = p; p += (size_t)NF * 128 * 128;
    u16* W2r = p; p += (size_t)NF * 128 * 128;
    u16* o0  = p; p += (size_t)BD * 128;
    u16* o1  = p; p += (size_t)BD * 128;
    u16* o2  = p; p += (size_t)BD * 128;

    prep_x0_k<<<BD * 64 / 256, 256, 0, stream>>>(emb_W, disc, dense_x, dense_proj, x0);
    prep_h0_k<<<BB * DIN_PAD / 256, 256, 0, stream>>>(emb_W, disc, dense_x, h0);
    transpose_pad_k<<<1024 * DIN_PAD / 256, 256, 0, stream>>>(W1, W1t, 429, 1024, DIN_PAD);
    transpose_pad_k<<<512 * 1024 / 256, 256, 0, stream>>>(W2, W2t, 1024, 512, 1024);
    transpose_pad_k<<<256 * 512 / 256, 256, 0, stream>>>(W3, W3t, 512, 256, 512);
    cinw_k<<<NF * 128 * 64 / 256, 256, 0, stream>>>(cin_W0, W0r, 39, 64);
    cinw_k<<<NF * 128 * 128 / 256, 256, 0, stream>>>(cin_W1, W1r, 128, 128);
    cinw_k<<<NF * 128 * 128 / 256, 256, 0, stream>>>(cin_W2, W2r, 128, 128);

    gemm_bn_relu_k<<<dim3(1024 / 64, BB / 64), 256, 0, stream>>>(h0, W1t, h1, BB, 1024, DIN_PAD, b1, g1, bb1);
    gemm_bn_relu_k<<<dim3(512 / 64, BB / 64), 256, 0, stream>>>(h1, W2t, h2, BB, 512, 1024, b2, g2, bb2);
    gemm_bn_relu_k<<<dim3(256 / 64, BB / 64), 256, 0, stream>>>(h2, W3t, h3, BB, 256, 512, b3, g3, bb3);

    cin_layer_k<64><<<BD / 128, 256, 0, stream>>>(x0, x0, W0r, o0);
    cin_layer_k<128><<<BD / 128, 256, 0, stream>>>(o0, x0, W1r, o1);
    cin_layer_k<128><<<BD / 128, 256, 0, stream>>>(o1, x0, W2r, o2);

    final_k<<<BB, 64, 0, stream>>>(dense_x, disc, lin_emb, dense_W, dense_b,
                                   h3, Wout, bout, o0, o1, o2, cin_ow, cin_ob, (float*)d_out);
}

// Round 3
// 723.314 us; speedup vs baseline: 1.2535x; 1.2535x over previous
//
#include <hip/hip_runtime.h>

typedef unsigned short u16;
typedef unsigned int u32;
typedef __attribute__((ext_vector_type(8))) short bf16x8;
typedef __attribute__((ext_vector_type(4))) float f32x4;

#define BB 4096
#define NS 26
#define DNS 13
#define DD 16
#define VV 100000
#define FF 128
#define NF 39
#define BD 65536
#define DIN_PAD 448

__device__ __forceinline__ float bf2f(u16 x) {
    union { u32 u; float f; } v; v.u = ((u32)x) << 16; return v.f;
}
__device__ __forceinline__ u16 f2bf(float f) {
    union { float f; u32 u; } v; v.f = f;
    u32 u = v.u;
    u32 r = (u + 0x7fffu + ((u >> 16) & 1u)) >> 16;
    return (u16)r;
}

// ---------------- prep kernels (f32 in -> bf16 workspace) ----------------

__global__ void prep_x0_k(const float* __restrict__ emb_W, const int* __restrict__ disc,
                          const float* __restrict__ dense_x, const float* __restrict__ dense_proj,
                          u16* __restrict__ x0) {
    int e = blockIdx.x * 256 + threadIdx.x;   // BD*64
    int c = e & 63;
    int j = e >> 6;
    int b = j >> 4, d = j & 15;
    float v = 0.f;
    if (c < NS) {
        int ix = disc[b * NS + c];
        v = emb_W[((size_t)c * VV + ix) * DD + d];
    } else if (c < NF) {
        int q = c - NS;
        v = dense_x[b * DNS + q] * dense_proj[q * DD + d];
    }
    x0[e] = f2bf(v);
}

__global__ void prep_h0_k(const float* __restrict__ emb_W, const int* __restrict__ disc,
                          const float* __restrict__ dense_x, u16* __restrict__ h0) {
    int e = blockIdx.x * 256 + threadIdx.x;   // B*448
    int col = e % DIN_PAD;
    int b = e / DIN_PAD;
    float v = 0.f;
    if (col < NS * DD) {
        int n = col >> 4, d = col & 15;
        int ix = disc[b * NS + n];
        v = emb_W[((size_t)n * VV + ix) * DD + d];
    } else if (col < NS * DD + DNS) {
        v = dense_x[b * DNS + col - NS * DD];
    }
    h0[e] = f2bf(v);
}

__global__ void transpose_pad_k(const float* __restrict__ src, u16* __restrict__ dst,
                                int K, int Nn, int Kpad) {
    int e = blockIdx.x * 256 + threadIdx.x;   // Nn*Kpad
    int n = e / Kpad, k = e % Kpad;
    dst[e] = (k < K) ? f2bf(src[(size_t)k * Nn + n]) : (u16)0;
}

// cin weight rearrange: dst[n][f][c(pad)] = W[f,c,n]
__global__ void cinw_k(const float* __restrict__ src, u16* __restrict__ dst, int C, int Cpad) {
    int e = blockIdx.x * 256 + threadIdx.x;   // 39*128*Cpad
    int n = e / (128 * Cpad);
    int rem = e % (128 * Cpad);
    int f = rem / Cpad, c = rem % Cpad;
    dst[e] = (c < C) ? f2bf(src[((size_t)f * C + c) * NF + n]) : (u16)0;
}

// ---------------- DNN GEMM: C = relu(bn(A@W + bias)) ----------------
// A [M,K] bf16 (K mult of 32), Bt [N,K] bf16 (pre-transposed W), C [M,N] bf16
__global__ __launch_bounds__(256) void gemm_bn_relu_k(
    const u16* __restrict__ A, const u16* __restrict__ Bt, u16* __restrict__ C,
    int M, int N, int K,
    const float* __restrict__ bias, const float* __restrict__ g, const float* __restrict__ bb)
{
    __shared__ u16 la[64 * 40];
    __shared__ u16 lb[64 * 40];
    const int tid = threadIdx.x;
    const int lane = tid & 63, wave = tid >> 6;
    const int quad = lane >> 4, l16 = lane & 15;
    const int m0 = blockIdx.y * 64, n0 = blockIdx.x * 64;
    const f32x4 fzero = {0.f, 0.f, 0.f, 0.f};
    f32x4 acc[4];
    #pragma unroll
    for (int t = 0; t < 4; ++t) acc[t] = fzero;
    const int r = tid >> 2, cc = (tid & 3) * 8;
    for (int k0 = 0; k0 < K; k0 += 32) {
        __syncthreads();
        *(int4*)&la[r * 40 + cc] = *(const int4*)&A[(size_t)(m0 + r) * K + k0 + cc];
        *(int4*)&lb[r * 40 + cc] = *(const int4*)&Bt[(size_t)(n0 + r) * K + k0 + cc];
        __syncthreads();
        bf16x8 af = *(const bf16x8*)&la[(wave * 16 + l16) * 40 + quad * 8];
        #pragma unroll
        for (int t = 0; t < 4; ++t) {
            bf16x8 bfm = *(const bf16x8*)&lb[(t * 16 + l16) * 40 + quad * 8];
            acc[t] = __builtin_amdgcn_mfma_f32_16x16x32_bf16(af, bfm, acc[t], 0, 0, 0);
        }
    }
    const float rs = rsqrtf(1.f + 1e-5f);
    #pragma unroll
    for (int t = 0; t < 4; ++t) {
        int n = n0 + t * 16 + l16;
        float bi = bias[n];
        float sc = g[n] * rs;
        float b2 = bb[n];
        #pragma unroll
        for (int rr = 0; rr < 4; ++rr) {
            int m = m0 + wave * 16 + quad * 4 + rr;
            float v = (acc[t][rr] + bi) * sc + b2;
            v = fmaxf(v, 0.f);
            C[(size_t)m * N + n] = f2bf(v);
        }
    }
}

// ---------------- CIN layer (barrier-free n-loop) ----------------
// Out[j,f] = sum_n x0[j,n] * sum_c W[f,c,n]*Xj[j,c]
// Xj [BD][CPAD], X0w [BD][64], Wr [39][128][CPAD], Out [BD][128]  (all bf16)
// Block: 512 threads = 8 waves; out tile 128j x 128f.
// Wave w: f-range (w&3)*32, j-half (w>>2)*64. B-frags (Xj) in VGPRs for all 39 n;
// A-frags (W_n) loaded global->reg, double-buffered; x0 scales from LDS.
#define LOADA(buf, n_) do { \
    _Pragma("unroll") for (int ms = 0; ms < 2; ++ms) \
    _Pragma("unroll") for (int kc = 0; kc < NCH; ++kc) \
        buf[ms][kc] = *(const bf16x8*)(ap[ms][kc] + (size_t)(n_) * WSTRIDE); \
} while (0)

#define LOADX(xv, n_) do { \
    _Pragma("unroll") for (int js = 0; js < 4; ++js) \
        xv[js] = bf2f(lx0[(jh * 64 + js * 16 + l16) * 72 + (n_)]); \
} while (0)

#define COMPUTE(A, xv) do { \
    _Pragma("unroll") for (int js = 0; js < 4; ++js) { \
        f32x4 s0 = fzero, s1 = fzero; \
        _Pragma("unroll") for (int kc = 0; kc < NCH; ++kc) { \
            s0 = __builtin_amdgcn_mfma_f32_16x16x32_bf16(A[0][kc], bfr[js][kc], s0, 0, 0, 0); \
            s1 = __builtin_amdgcn_mfma_f32_16x16x32_bf16(A[1][kc], bfr[js][kc], s1, 0, 0, 0); \
        } \
        acc[js][0] += xv[js] * s0; \
        acc[js][1] += xv[js] * s1; \
    } \
} while (0)

template <int CPAD>
__global__ __launch_bounds__(512, 2) void cin_layer_k(
    const u16* __restrict__ Xj, const u16* __restrict__ X0w,
    const u16* __restrict__ Wr, u16* __restrict__ Out)
{
    constexpr int NCH = CPAD / 32;
    constexpr size_t WSTRIDE = (size_t)128 * CPAD;   // W elems per n
    __shared__ u16 lx0[128 * 72];
    const int tid = threadIdx.x;
    const int lane = tid & 63, wave = tid >> 6;
    const int quad = lane >> 4, l16 = lane & 15;
    const int fw = wave & 3;      // f-range fw*32
    const int jh = wave >> 2;     // j-half jh*64
    const size_t j0 = (size_t)blockIdx.x * 128;
    const f32x4 fzero = {0.f, 0.f, 0.f, 0.f};

    // stage x0 scales [128 rows][64 cols] at stride 72
    for (int ch = tid; ch < 128 * 8; ch += 512) {
        int r = ch >> 3, c = (ch & 7) * 8;
        *(int4*)&lx0[r * 72 + c] = *(const int4*)&X0w[(j0 + r) * 64 + c];
    }

    // B-frags: this wave's 64 j rows of Xj, all K — held for the whole n-loop
    bf16x8 bfr[4][NCH];
    #pragma unroll
    for (int js = 0; js < 4; ++js)
        #pragma unroll
        for (int kc = 0; kc < NCH; ++kc)
            bfr[js][kc] = *(const bf16x8*)&Xj[(j0 + jh * 64 + js * 16 + l16) * CPAD + kc * 32 + quad * 8];

    // A-frag base pointers (n=0): W rows f for this wave
    const u16* ap[2][NCH];
    #pragma unroll
    for (int ms = 0; ms < 2; ++ms)
        #pragma unroll
        for (int kc = 0; kc < NCH; ++kc)
            ap[ms][kc] = &Wr[(size_t)(fw * 32 + ms * 16 + l16) * CPAD + kc * 32 + quad * 8];

    __syncthreads();   // lx0 ready (the only barrier before the epilogue)

    f32x4 acc[4][2];
    #pragma unroll
    for (int js = 0; js < 4; ++js) { acc[js][0] = fzero; acc[js][1] = fzero; }

    bf16x8 a0[2][NCH], a1[2][NCH];
    float xv0[4], xv1[4];
    LOADA(a0, 0); LOADX(xv0, 0);
    #pragma unroll 1
    for (int n = 0; n < NF - 1; n += 2) {
        LOADA(a1, n + 1); LOADX(xv1, n + 1);
        COMPUTE(a0, xv0);
        LOADA(a0, n + 2); LOADX(xv0, n + 2);
        COMPUTE(a1, xv1);
    }
    COMPUTE(a0, xv0);   // n = 38

    // store: D col(lane&15)=j, row(quad*4+r)=f
    #pragma unroll
    for (int js = 0; js < 4; ++js) {
        size_t jrow = j0 + jh * 64 + js * 16 + l16;
        #pragma unroll
        for (int ms = 0; ms < 2; ++ms) {
            f32x4 v = acc[js][ms];
            uint2 pk;
            pk.x = (u32)f2bf(v[0]) | ((u32)f2bf(v[1]) << 16);
            pk.y = (u32)f2bf(v[2]) | ((u32)f2bf(v[3]) << 16);
            *(uint2*)&Out[jrow * 128 + fw * 32 + ms * 16 + quad * 4] = pk;
        }
    }
}
#undef LOADA
#undef LOADX
#undef COMPUTE

// ---------------- final combine ----------------
__global__ __launch_bounds__(64) void final_k(
    const float* __restrict__ dense_x, const int* __restrict__ disc,
    const float* __restrict__ lin_emb, const float* __restrict__ dense_W,
    const float* __restrict__ dense_b, const u16* __restrict__ h3,
    const float* __restrict__ Wout, const float* __restrict__ bout,
    const u16* __restrict__ out0, const u16* __restrict__ out1, const u16* __restrict__ out2,
    const float* __restrict__ cw, const float* __restrict__ cb, float* __restrict__ out)
{
    const int b = blockIdx.x;
    const int lane = threadIdx.x;
    float t = 0.f;
    if (lane < DNS) {
        t += dense_x[b * DNS + lane] * dense_W[lane];
    } else if (lane < DNS + NS) {
        int i = lane - DNS;
        t += lin_emb[(size_t)i * VV + disc[b * NS + i]];
    }
    const u16* hr = h3 + (size_t)b * 256;
    #pragma unroll
    for (int rr = 0; rr < 4; ++rr) {
        int c = lane * 4 + rr;
        t += bf2f(hr[c]) * Wout[c];
    }
    const u16* obs[3] = {out0, out1, out2};
    #pragma unroll
    for (int L = 0; L < 3; ++L) {
        const u16* ob = obs[L] + (size_t)b * 16 * 128;
        #pragma unroll
        for (int h = 0; h < 2; ++h) {
            int f = lane + h * 64;
            float p = 0.f;
            #pragma unroll
            for (int d = 0; d < 16; ++d) p += bf2f(ob[d * 128 + f]);
            t += p * cw[L * 128 + f];
        }
    }
    #pragma unroll
    for (int off = 32; off > 0; off >>= 1) t += __shfl_down(t, off, 64);
    if (lane == 0) out[b] = t + dense_b[0] + bout[0] + cb[0];
}

// ---------------- launch ----------------
extern "C" void kernel_launch(void* const* d_in, const int* in_sizes, int n_in,
                              void* d_out, int out_size, void* d_ws, size_t ws_size,
                              hipStream_t stream) {
    const float* dense_x = (const float*)d_in[0];
    const int* disc      = (const int*)d_in[1];
    const float* lin_emb = (const float*)d_in[2];
    const float* emb_W   = (const float*)d_in[3];
    const float* dense_W = (const float*)d_in[4];
    const float* dense_b = (const float*)d_in[5];
    const float* W1  = (const float*)d_in[6];
    const float* b1  = (const float*)d_in[7];
    const float* g1  = (const float*)d_in[8];
    const float* bb1 = (const float*)d_in[9];
    const float* W2  = (const float*)d_in[10];
    const float* b2  = (const float*)d_in[11];
    const float* g2  = (const float*)d_in[12];
    const float* bb2 = (const float*)d_in[13];
    const float* W3  = (const float*)d_in[14];
    const float* b3  = (const float*)d_in[15];
    const float* g3  = (const float*)d_in[16];
    const float* bb3 = (const float*)d_in[17];
    const float* Wout = (const float*)d_in[18];
    const float* bout = (const float*)d_in[19];
    const float* dense_proj = (const float*)d_in[20];
    const float* cin_W0 = (const float*)d_in[21];
    const float* cin_W1 = (const float*)d_in[22];
    const float* cin_W2 = (const float*)d_in[23];
    const float* cin_ow = (const float*)d_in[24];
    const float* cin_ob = (const float*)d_in[25];

    u16* p = (u16*)d_ws;
    u16* x0  = p; p += (size_t)BD * 64;
    u16* h0  = p; p += (size_t)BB * DIN_PAD;
    u16* h1  = p; p += (size_t)BB * 1024;
    u16* h2  = p; p += (size_t)BB * 512;
    u16* h3  = p; p += (size_t)BB * 256;
    u16* W1t = p; p += (size_t)1024 * DIN_PAD;
    u16* W2t = p; p += (size_t)512 * 1024;
    u16* W3t = p; p += (size_t)256 * 512;
    u16* W0r = p; p += (size_t)NF * 128 * 64;
    u16* W1r = p; p += (size_t)NF * 128 * 128;
    u16* W2r = p; p += (size_t)NF * 128 * 128;
    u16* o0  = p; p += (size_t)BD * 128;
    u16* o1  = p; p += (size_t)BD * 128;
    u16* o2  = p; p += (size_t)BD * 128;

    prep_x0_k<<<BD * 64 / 256, 256, 0, stream>>>(emb_W, disc, dense_x, dense_proj, x0);
    prep_h0_k<<<BB * DIN_PAD / 256, 256, 0, stream>>>(emb_W, disc, dense_x, h0);
    transpose_pad_k<<<1024 * DIN_PAD / 256, 256, 0, stream>>>(W1, W1t, 429, 1024, DIN_PAD);
    transpose_pad_k<<<512 * 1024 / 256, 256, 0, stream>>>(W2, W2t, 1024, 512, 1024);
    transpose_pad_k<<<256 * 512 / 256, 256, 0, stream>>>(W3, W3t, 512, 256, 512);
    cinw_k<<<NF * 128 * 64 / 256, 256, 0, stream>>>(cin_W0, W0r, 39, 64);
    cinw_k<<<NF * 128 * 128 / 256, 256, 0, stream>>>(cin_W1, W1r, 128, 128);
    cinw_k<<<NF * 128 * 128 / 256, 256, 0, stream>>>(cin_W2, W2r, 128, 128);

    gemm_bn_relu_k<<<dim3(1024 / 64, BB / 64), 256, 0, stream>>>(h0, W1t, h1, BB, 1024, DIN_PAD, b1, g1, bb1);
    gemm_bn_relu_k<<<dim3(512 / 64, BB / 64), 256, 0, stream>>>(h1, W2t, h2, BB, 512, 1024, b2, g2, bb2);
    gemm_bn_relu_k<<<dim3(256 / 64, BB / 64), 256, 0, stream>>>(h2, W3t, h3, BB, 256, 512, b3, g3, bb3);

    cin_layer_k<64><<<BD / 128, 512, 0, stream>>>(x0, x0, W0r, o0);
    cin_layer_k<128><<<BD / 128, 512, 0, stream>>>(o0, x0, W1r, o1);
    cin_layer_k<128><<<BD / 128, 512, 0, stream>>>(o1, x0, W2r, o2);

    final_k<<<BB, 64, 0, stream>>>(dense_x, disc, lin_emb, dense_W, dense_b,
                                   h3, Wout, bout, o0, o1, o2, cin_ow, cin_ob, (float*)d_out);
}